// Round 5
// baseline (496.531 us; speedup 1.0000x reference)
//
#include <hip/hip_runtime.h>

// Problem constants (n_steps==64 fixed for this instance).
#define BDIM 4096
#define DX 512
#define DZ 512
#define DY 256
#define HD 2048
#define NSTEPS 64
#define NBLK 128  // chain_coop grid size (<= 256 CUs => all co-resident)

typedef __attribute__((ext_vector_type(8))) short bf16x8;   // 8 bf16 = 4 VGPRs
typedef __attribute__((ext_vector_type(4))) float f32x4;

__device__ inline unsigned short f2bf(float f) {  // RNE f32 -> bf16
    unsigned u = __float_as_uint(f);
    unsigned r = 0x7FFFu + ((u >> 16) & 1u);
    return (unsigned short)((u + r) >> 16);
}
__device__ inline float bf2f(unsigned short h) {
    return __uint_as_float(((unsigned)h) << 16);
}

// async global->LDS, 16B/lane (used ONLY in the proven gemm_bf16)
#define GLDS16(g, l)                                                            \
    __builtin_amdgcn_global_load_lds((const __attribute__((address_space(1))) void*)(g), \
                                     (__attribute__((address_space(3))) void*)(l), 16, 0, 0)

// ---------------------------------------------------------------------------
// Workspace byte offsets (shared host/device; all 64B-aligned)
constexpr size_t ELS = (size_t)DZ * DZ;  // 262144
constexpr size_t OFF_BAR = 0;
constexpr size_t OFF_XB  = 64;
constexpr size_t OFF_W2B = OFF_XB  + (size_t)BDIM * DX * 2;
constexpr size_t OFF_W3B = OFF_W2B + (size_t)HD * HD * 2;
constexpr size_t OFF_W1H = OFF_W3B + (size_t)DY * HD * 2;
constexpr size_t OFF_W1L = OFF_W1H + (size_t)HD * DZ * 2;
constexpr size_t OFF_AH  = OFF_W1L + (size_t)HD * DZ * 2;
constexpr size_t OFF_AL  = OFF_AH  + ELS * 2;
constexpr size_t OFF_PH  = OFF_AL  + ELS * 2;
constexpr size_t OFF_PL  = OFF_PH  + ELS * 2;
constexpr size_t OFF_M2F = OFF_PL  + ELS * 2;
constexpr size_t OFF_M3F = OFF_M2F + ELS * 4;
constexpr size_t OFF_M4F = OFF_M3F + ELS * 4;
constexpr size_t OFF_M2H = OFF_M4F + ELS * 4;
constexpr size_t OFF_M2L = OFF_M2H + ELS * 2;
constexpr size_t OFF_SH0 = OFF_M2L + ELS * 2;
constexpr size_t OFF_SL0 = OFF_SH0 + ELS * 2;
constexpr size_t OFF_SH1 = OFF_SL0 + ELS * 2;
constexpr size_t OFF_SL1 = OFF_SH1 + ELS * 2;
constexpr size_t OFF_RH  = OFF_SL1 + ELS * 2;
constexpr size_t OFF_RL  = OFF_RH  + ELS * 2;
constexpr size_t OFF_C1B = OFF_RL  + ELS * 2;
constexpr size_t OFF_H1B = OFF_C1B + (size_t)HD * DZ * 2;
constexpr size_t OFF_H2B = OFF_H1B + (size_t)BDIM * HD * 2;
// end ~60 MB

// ---------------------------------------------------------------------------
// Batched f32 -> bf16 convert; lo-part optional. Also zeroes the grid barrier.
struct CvtJobs {
    const float* src[6];
    unsigned short* hi[6];
    unsigned short* lo[6];   // null -> hi only
    int n4[6];               // element count / 4
    unsigned* bar;
};
__global__ __launch_bounds__(256) void cvt_multi_k(CvtJobs J) {
    if (blockIdx.x == 0 && blockIdx.y == 0 && threadIdx.x == 0) atomicExch(J.bar, 0u);
    const int j = blockIdx.y;
    const int i4 = blockIdx.x * 256 + threadIdx.x;
    if (i4 >= J.n4[j]) return;
    float4 v = ((const float4*)J.src[j])[i4];
    ushort4 h;
    h.x = f2bf(v.x); h.y = f2bf(v.y); h.z = f2bf(v.z); h.w = f2bf(v.w);
    ((ushort4*)J.hi[j])[i4] = h;
    if (J.lo[j]) {
        ushort4 l;
        l.x = f2bf(v.x - bf2f(h.x));
        l.y = f2bf(v.y - bf2f(h.y));
        l.z = f2bf(v.z - bf2f(h.z));
        l.w = f2bf(v.w - bf2f(h.w));
        ((ushort4*)J.lo[j])[i4] = l;
    }
}

// ---------------------------------------------------------------------------
// Device-scope grid barrier: release fence -> arrive -> poll -> acquire fence.
// All NBLK blocks co-resident (grid <= CU count), so no deadlock.
__device__ __forceinline__ void gbar(unsigned* bar, unsigned& gen) {
    gen += NBLK;
    __syncthreads();
    if (threadIdx.x == 0) {
        __threadfence();                       // release (agent scope, writes back L2)
        atomicAdd(bar, 1u);
        while (atomicAdd(bar, 0u) < gen)       // device-scope RMW poll (bypasses stale L2)
            __builtin_amdgcn_s_sleep(2);
    }
    __syncthreads();
    __threadfence();                           // acquire (invalidate stale lines)
}

// ---------------------------------------------------------------------------
// One 64x64 NN split-bf16 GEMM tile (round-4-proven body, VGPR->LDS staging).
// C[trow*64.., tcol*64..] = A[M,K] @ B[K,N]; A split hi/lo [.,K], B split [K,N].
__device__ __forceinline__ void g64_tile(int trow, int tcol, int N, int K,
                                         const unsigned short* Ahi, const unsigned short* Alo,
                                         const unsigned short* Bhi, const unsigned short* Blo,
                                         float* Cf32, unsigned short* Chi, unsigned short* Clo,
                                         unsigned short* LA, unsigned short* LAl,
                                         unsigned short* LB, unsigned short* LBl) {
    const int tid = threadIdx.x;
    const int lane = tid & 63;
    const int wave = tid >> 6;
    const int wr = wave >> 1, wc = wave & 1;
    const int row0 = trow * 64, col0 = tcol * 64;
    const int am = tid >> 2, ak = (tid & 3) * 8;   // A stage: [64][32]
    const int bk = tid >> 3, bn = (tid & 7) * 8;   // B stage: [32][64]

    f32x4 acc[4] = {};

    for (int k0 = 0; k0 < K; k0 += 32) {
        bf16x8 avh = *(const bf16x8*)(Ahi + (size_t)(row0 + am) * K + k0 + ak);
        bf16x8 avl = *(const bf16x8*)(Alo + (size_t)(row0 + am) * K + k0 + ak);
        bf16x8 bvh = *(const bf16x8*)(Bhi + (size_t)(k0 + bk) * N + col0 + bn);
        bf16x8 bvl = *(const bf16x8*)(Blo + (size_t)(k0 + bk) * N + col0 + bn);
        __syncthreads();  // protect previous LDS consumers (prev iter / prev tile / prev phase)
        *(bf16x8*)&LA[am * 32 + ak] = avh;
        *(bf16x8*)&LAl[am * 32 + ak] = avl;
        *(bf16x8*)&LB[bk * 64 + bn] = bvh;
        *(bf16x8*)&LBl[bk * 64 + bn] = bvl;
        __syncthreads();  // publish

        const int kk = (lane >> 4) * 8;
        const int mrow = wr * 32 + (lane & 15);
        const int ncol = wc * 32 + (lane & 15);
        bf16x8 ah[2], al8[2], bh[2], bl8[2];
#pragma unroll
        for (int t = 0; t < 2; ++t) {
            ah[t] = *(const bf16x8*)&LA[(mrow + t * 16) * 32 + kk];
            al8[t] = *(const bf16x8*)&LAl[(mrow + t * 16) * 32 + kk];
#pragma unroll
            for (int j = 0; j < 8; ++j) {
                bh[t][j] = (short)LB[(kk + j) * 64 + ncol + t * 16];
                bl8[t][j] = (short)LBl[(kk + j) * 64 + ncol + t * 16];
            }
        }
#pragma unroll
        for (int mt = 0; mt < 2; ++mt)
#pragma unroll
            for (int nt = 0; nt < 2; ++nt) {
                acc[mt * 2 + nt] = __builtin_amdgcn_mfma_f32_16x16x32_bf16(
                    ah[mt], bh[nt], acc[mt * 2 + nt], 0, 0, 0);
                acc[mt * 2 + nt] = __builtin_amdgcn_mfma_f32_16x16x32_bf16(
                    ah[mt], bl8[nt], acc[mt * 2 + nt], 0, 0, 0);
                acc[mt * 2 + nt] = __builtin_amdgcn_mfma_f32_16x16x32_bf16(
                    al8[mt], bh[nt], acc[mt * 2 + nt], 0, 0, 0);
            }
    }

    // epilogue — C/D layout: col=lane&15, row=(lane>>4)*4+reg
#pragma unroll
    for (int mt = 0; mt < 2; ++mt) {
        const int grow = row0 + wr * 32 + mt * 16 + (lane >> 4) * 4;
#pragma unroll
        for (int nt = 0; nt < 2; ++nt) {
            const int gcol = col0 + wc * 32 + nt * 16 + (lane & 15);
#pragma unroll
            for (int i = 0; i < 4; ++i) {
                float x = acc[mt * 2 + nt][i];
                const size_t off = (size_t)(grow + i) * N + gcol;
                if (Cf32) Cf32[off] = x;
                unsigned short hh = f2bf(x);
                if (Chi) Chi[off] = hh;
                if (Clo) Clo[off] = f2bf(x - bf2f(hh));
            }
        }
    }
}

// ---------------------------------------------------------------------------
// The whole 512-matrix chain in one launch, phases separated by grid barriers:
//   M2=A@A -> {M3=M2@A || M4=M2@M2} -> S=taylor4 -> S^64 (6 squarings)
//   -> R=Q@P -> C1=W1@R
__global__ __launch_bounds__(256, 1) void chain_coop(const float* __restrict__ Am, char* ws) {
    __shared__ unsigned short LA[64 * 32], LAl[64 * 32], LB[32 * 64], LBl[32 * 64];
    unsigned* bar = (unsigned*)(ws + OFF_BAR);
    unsigned short* Ah  = (unsigned short*)(ws + OFF_AH);
    unsigned short* Al_ = (unsigned short*)(ws + OFF_AL);
    unsigned short* Ph  = (unsigned short*)(ws + OFF_PH);
    unsigned short* Pl  = (unsigned short*)(ws + OFF_PL);
    float* M2f = (float*)(ws + OFF_M2F);
    float* M3f = (float*)(ws + OFF_M3F);
    float* M4f = (float*)(ws + OFF_M4F);
    unsigned short* M2h = (unsigned short*)(ws + OFF_M2H);
    unsigned short* M2l = (unsigned short*)(ws + OFF_M2L);
    unsigned short* shb[2] = {(unsigned short*)(ws + OFF_SH0), (unsigned short*)(ws + OFF_SH1)};
    unsigned short* slb[2] = {(unsigned short*)(ws + OFF_SL0), (unsigned short*)(ws + OFF_SL1)};
    unsigned short* Rh  = (unsigned short*)(ws + OFF_RH);
    unsigned short* Rl  = (unsigned short*)(ws + OFF_RL);
    unsigned short* W1h = (unsigned short*)(ws + OFF_W1H);
    unsigned short* W1l = (unsigned short*)(ws + OFF_W1L);
    unsigned short* C1b = (unsigned short*)(ws + OFF_C1B);

    unsigned gen = 0;
    const int blk = blockIdx.x;  // 0..127

    // P0: M2 = A@A (64 tiles; blocks 64..127 idle)
    if (blk < 64)
        g64_tile(blk >> 3, blk & 7, DZ, DZ, Ah, Al_, Ah, Al_, M2f, M2h, M2l, LA, LAl, LB, LBl);
    gbar(bar, gen);

    // P1: M3 = M2@A ; M4 = M2@M2 (128 tiles, full grid)
    if (blk < 64)
        g64_tile(blk >> 3, blk & 7, DZ, DZ, M2h, M2l, Ah, Al_, M3f, nullptr, nullptr,
                 LA, LAl, LB, LBl);
    else
        g64_tile((blk - 64) >> 3, (blk - 64) & 7, DZ, DZ, M2h, M2l, M2h, M2l, M4f,
                 nullptr, nullptr, LA, LAl, LB, LBl);
    gbar(bar, gen);

    // P2: S = I + h*A + c2*M2 + c3*M3 + c4*M4 (split out), 8 elems/thread
    {
        const float hh = 1.0f / (float)NSTEPS;
        const float c2 = 0.5f * hh * hh;
        const float c3 = hh * hh * hh * (1.0f / 6.0f);
        const float c4 = hh * hh * hh * hh * (1.0f / 24.0f);
        const int base = (blk * 256 + threadIdx.x) * 8;  // 128*256*8 == 512*512 exactly
        const int row = base >> 9, colb = base & 511;
        const int d = row - colb;  // diagonal offset within the 8-group
#pragma unroll
        for (int j = 0; j < 8; ++j) {
            const int idx = base + j;
            float s = hh * Am[idx] + c2 * M2f[idx] + c3 * M3f[idx] + c4 * M4f[idx];
            if (j == d) s += 1.0f;
            unsigned short hi = f2bf(s);
            shb[0][idx] = hi;
            slb[0][idx] = f2bf(s - bf2f(hi));
        }
    }
    gbar(bar, gen);

    // P3..P8: Q = S^64 via 6 squarings (ping-pong; ends in buffer 0)
    int cur = 0;
    for (int s = 0; s < 6; ++s) {
        if (blk < 64)
            g64_tile(blk >> 3, blk & 7, DZ, DZ, shb[cur], slb[cur], shb[cur], slb[cur],
                     nullptr, shb[1 - cur], slb[1 - cur], LA, LAl, LB, LBl);
        gbar(bar, gen);
        cur ^= 1;
    }

    // P9: R = Q @ P  [Dz, Dx]
    if (blk < 64)
        g64_tile(blk >> 3, blk & 7, DZ, DZ, shb[0], slb[0], Ph, Pl,
                 nullptr, Rh, Rl, LA, LAl, LB, LBl);
    gbar(bar, gen);

    // P10: C1 = W1 @ R  [H, Dx] = 32x8 = 256 tiles, 2 per block
    {
        const int t0 = blk, t1 = blk + NBLK;
        g64_tile(t0 >> 3, t0 & 7, DZ, DZ, W1h, W1l, Rh, Rl, nullptr, C1b, nullptr,
                 LA, LAl, LB, LBl);
        g64_tile(t1 >> 3, t1 & 7, DZ, DZ, W1h, W1l, Rh, Rl, nullptr, C1b, nullptr,
                 LA, LAl, LB, LBl);
    }
}

// ---------------------------------------------------------------------------
// Big bf16 MFMA GEMM (proven): C[M,N] = A[M,K] @ B[N,K]^T (+bias)(relu)
// 128x128 tile, BK=32, 4 waves 2x2 (each 64x64).
template <int RELU, int BIAS, int OUT_BF16>
__global__ __launch_bounds__(256) void gemm_bf16(int M, int N, int K,
                                                 const unsigned short* __restrict__ A,
                                                 const unsigned short* __restrict__ B,
                                                 void* __restrict__ C,
                                                 const float* __restrict__ bias) {
    __shared__ unsigned short As[128 * 32];
    __shared__ unsigned short Bs[128 * 32];

    const int tid = threadIdx.x;
    const int lane = tid & 63;
    const int wave = tid >> 6;
    const int wr = wave >> 1, wc = wave & 1;
    const int row0 = blockIdx.y * 128;
    const int col0 = blockIdx.x * 128;

    const int srow = lane >> 2;
    const int schunk = (lane & 3) * 8;

    f32x4 acc[4][4] = {};

    for (int k0 = 0; k0 < K; k0 += 32) {
        const int r0 = wave * 32;
        GLDS16(A + (size_t)(row0 + r0 + srow) * K + k0 + schunk, &As[r0 * 32]);
        GLDS16(A + (size_t)(row0 + r0 + 16 + srow) * K + k0 + schunk, &As[(r0 + 16) * 32]);
        GLDS16(B + (size_t)(col0 + r0 + srow) * K + k0 + schunk, &Bs[r0 * 32]);
        GLDS16(B + (size_t)(col0 + r0 + 16 + srow) * K + k0 + schunk, &Bs[(r0 + 16) * 32]);
        __syncthreads();

        const int kk = (lane >> 4) * 8;
        const int mbase = wr * 64 + (lane & 15);
        const int nbase = wc * 64 + (lane & 15);
        bf16x8 af[4], bf[4];
#pragma unroll
        for (int t = 0; t < 4; ++t) {
            af[t] = *(const bf16x8*)&As[(mbase + t * 16) * 32 + kk];
            bf[t] = *(const bf16x8*)&Bs[(nbase + t * 16) * 32 + kk];
        }
#pragma unroll
        for (int mt = 0; mt < 4; ++mt)
#pragma unroll
            for (int nt = 0; nt < 4; ++nt)
                acc[mt][nt] = __builtin_amdgcn_mfma_f32_16x16x32_bf16(af[mt], bf[nt],
                                                                      acc[mt][nt], 0, 0, 0);
        __syncthreads();
    }

#pragma unroll
    for (int mt = 0; mt < 4; ++mt) {
        const int grow = row0 + wr * 64 + mt * 16 + (lane >> 4) * 4;
#pragma unroll
        for (int nt = 0; nt < 4; ++nt) {
            const int gcol = col0 + wc * 64 + nt * 16 + (lane & 15);
            const float bv = BIAS ? bias[gcol] : 0.0f;
#pragma unroll
            for (int i = 0; i < 4; ++i) {
                float v = acc[mt][nt][i] + bv;
                if (RELU) v = fmaxf(v, 0.0f);
                const size_t off = (size_t)(grow + i) * N + gcol;
                if (OUT_BF16)
                    ((unsigned short*)C)[off] = f2bf(v);
                else
                    ((float*)C)[off] = v;
            }
        }
    }
}

// ---------------------------------------------------------------------------
// 64x64 NT bf16 GEMM, fp32 out + bias (for y: N=256 -> 256 blocks).
// VGPR->LDS staging, no GLDS.
__global__ __launch_bounds__(256) void gemm64nt_f32(int M, int N, int K,
                                                    const unsigned short* __restrict__ A,
                                                    const unsigned short* __restrict__ B,
                                                    float* __restrict__ C,
                                                    const float* __restrict__ bias) {
    __shared__ unsigned short As[64 * 32];
    __shared__ unsigned short Bs[64 * 32];
    const int tid = threadIdx.x;
    const int lane = tid & 63;
    const int wave = tid >> 6;
    const int wr = wave >> 1, wc = wave & 1;
    const int row0 = blockIdx.y * 64;
    const int col0 = blockIdx.x * 64;
    const int r = tid >> 2, kq = (tid & 3) * 8;

    f32x4 acc[4] = {};

    for (int k0 = 0; k0 < K; k0 += 32) {
        bf16x8 av = *(const bf16x8*)(A + (size_t)(row0 + r) * K + k0 + kq);
        bf16x8 bv = *(const bf16x8*)(B + (size_t)(col0 + r) * K + k0 + kq);
        __syncthreads();
        *(bf16x8*)&As[r * 32 + kq] = av;
        *(bf16x8*)&Bs[r * 32 + kq] = bv;
        __syncthreads();

        const int kk = (lane >> 4) * 8;
        const int mb = wr * 32 + (lane & 15);
        const int nb = wc * 32 + (lane & 15);
        bf16x8 af[2], bf[2];
#pragma unroll
        for (int t = 0; t < 2; ++t) {
            af[t] = *(const bf16x8*)&As[(mb + t * 16) * 32 + kk];
            bf[t] = *(const bf16x8*)&Bs[(nb + t * 16) * 32 + kk];
        }
#pragma unroll
        for (int mt = 0; mt < 2; ++mt)
#pragma unroll
            for (int nt = 0; nt < 2; ++nt)
                acc[mt * 2 + nt] = __builtin_amdgcn_mfma_f32_16x16x32_bf16(
                    af[mt], bf[nt], acc[mt * 2 + nt], 0, 0, 0);
    }

#pragma unroll
    for (int mt = 0; mt < 2; ++mt) {
        const int grow = row0 + wr * 32 + mt * 16 + (lane >> 4) * 4;
#pragma unroll
        for (int nt = 0; nt < 2; ++nt) {
            const int gcol = col0 + wc * 32 + nt * 16 + (lane & 15);
            const float bv = bias ? bias[gcol] : 0.0f;
#pragma unroll
            for (int i = 0; i < 4; ++i)
                C[(size_t)(grow + i) * N + gcol] = acc[mt * 2 + nt][i] + bv;
        }
    }
}

// ---------------------------------------------------------------------------
extern "C" void kernel_launch(void* const* d_in, const int* in_sizes, int n_in,
                              void* d_out, int out_size, void* d_ws, size_t ws_size,
                              hipStream_t stream) {
    const float* X  = (const float*)d_in[0];  // [B, Dx]
    const float* P  = (const float*)d_in[1];  // [Dz, Dx]
    const float* Am = (const float*)d_in[2];  // [Dz, Dz]
    const float* W1 = (const float*)d_in[3];  // [H, Dz]
    const float* b1 = (const float*)d_in[4];
    const float* W2 = (const float*)d_in[5];  // [H, H]
    const float* b2 = (const float*)d_in[6];
    const float* W3 = (const float*)d_in[7];  // [Dy, H]
    const float* b3 = (const float*)d_in[8];
    float* out = (float*)d_out;               // [B, Dy] fp32

    char* ws = (char*)d_ws;
    unsigned short* Xb  = (unsigned short*)(ws + OFF_XB);
    unsigned short* W2b = (unsigned short*)(ws + OFF_W2B);
    unsigned short* W3b = (unsigned short*)(ws + OFF_W3B);
    unsigned short* W1h = (unsigned short*)(ws + OFF_W1H);
    unsigned short* W1l = (unsigned short*)(ws + OFF_W1L);
    unsigned short* Ah  = (unsigned short*)(ws + OFF_AH);
    unsigned short* Al  = (unsigned short*)(ws + OFF_AL);
    unsigned short* Ph  = (unsigned short*)(ws + OFF_PH);
    unsigned short* Pl  = (unsigned short*)(ws + OFF_PL);
    unsigned short* C1b = (unsigned short*)(ws + OFF_C1B);
    unsigned short* h1b = (unsigned short*)(ws + OFF_H1B);
    unsigned short* h2b = (unsigned short*)(ws + OFF_H2B);

    // ---- 1 launch: all input converts / splits + barrier init ----
    CvtJobs J;
    J.src[0] = X;  J.hi[0] = Xb;  J.lo[0] = nullptr; J.n4[0] = BDIM * DX / 4;
    J.src[1] = W2; J.hi[1] = W2b; J.lo[1] = nullptr; J.n4[1] = HD * HD / 4;
    J.src[2] = W3; J.hi[2] = W3b; J.lo[2] = nullptr; J.n4[2] = DY * HD / 4;
    J.src[3] = W1; J.hi[3] = W1h; J.lo[3] = W1l;     J.n4[3] = HD * DZ / 4;
    J.src[4] = Am; J.hi[4] = Ah;  J.lo[4] = Al;      J.n4[4] = (int)(ELS / 4);
    J.src[5] = P;  J.hi[5] = Ph;  J.lo[5] = Pl;      J.n4[5] = (int)(ELS / 4);
    J.bar = (unsigned*)(ws + OFF_BAR);
    cvt_multi_k<<<dim3(HD * HD / 4 / 256, 6), 256, 0, stream>>>(J);

    // ---- 1 launch: entire 512-chain (M2..C1) with internal grid barriers ----
    chain_coop<<<dim3(NBLK), 256, 0, stream>>>(Am, ws);

    // h1 = relu(X @ C1^T + b1)   [B, H], K=Dx
    gemm_bf16<1, 1, 1><<<dim3(HD / 128, BDIM / 128), 256, 0, stream>>>(
        BDIM, HD, DX, Xb, C1b, h1b, b1);
    // h2 = relu(h1 @ W2^T + b2)  [B, H]
    gemm_bf16<1, 1, 1><<<dim3(HD / 128, BDIM / 128), 256, 0, stream>>>(
        BDIM, HD, HD, h1b, W2b, h2b, b2);
    // y = h2 @ W3^T + b3         [B, Dy] fp32 out — 64-tile => 256 blocks
    gemm64nt_f32<<<dim3(DY / 64, BDIM / 64), 256, 0, stream>>>(
        BDIM, DY, HD, h2b, W3b, out, b3);
}

// Round 6
// 303.419 us; speedup vs baseline: 1.6365x; 1.6365x over previous
//
#include <hip/hip_runtime.h>

// Problem constants (n_steps==64 fixed for this instance).
#define BDIM 4096
#define DX 512
#define DZ 512
#define DY 256
#define HD 2048
#define NSTEPS 64
#define LDT 72  // padded LDS row (shorts): 144B stride -> ~conflict-free b128

typedef __attribute__((ext_vector_type(8))) short bf16x8;   // 8 bf16 = 4 VGPRs
typedef __attribute__((ext_vector_type(4))) float f32x4;

__device__ inline unsigned short f2bf(float f) {  // RNE f32 -> bf16
    unsigned u = __float_as_uint(f);
    unsigned r = 0x7FFFu + ((u >> 16) & 1u);
    return (unsigned short)((u + r) >> 16);
}
__device__ inline float bf2f(unsigned short h) {
    return __uint_as_float(((unsigned)h) << 16);
}

// async global->LDS, 16B/lane (used ONLY in the proven gemm_bf16)
#define GLDS16(g, l)                                                            \
    __builtin_amdgcn_global_load_lds((const __attribute__((address_space(1))) void*)(g), \
                                     (__attribute__((address_space(3))) void*)(l), 16, 0, 0)

// ---------------------------------------------------------------------------
// Batched f32 -> bf16 convert; lo-part optional (hi/lo split).
struct CvtJobs {
    const float* src[5];
    unsigned short* hi[5];
    unsigned short* lo[5];   // null -> hi only
    int n4[5];               // element count / 4
};
__global__ __launch_bounds__(256) void cvt_multi_k(CvtJobs J) {
    const int j = blockIdx.y;
    const int i4 = blockIdx.x * 256 + threadIdx.x;
    if (i4 >= J.n4[j]) return;
    float4 v = ((const float4*)J.src[j])[i4];
    ushort4 h;
    h.x = f2bf(v.x); h.y = f2bf(v.y); h.z = f2bf(v.z); h.w = f2bf(v.w);
    ((ushort4*)J.hi[j])[i4] = h;
    if (J.lo[j]) {
        ushort4 l;
        l.x = f2bf(v.x - bf2f(h.x));
        l.y = f2bf(v.y - bf2f(h.y));
        l.z = f2bf(v.z - bf2f(h.z));
        l.w = f2bf(v.w - bf2f(h.w));
        ((ushort4*)J.lo[j])[i4] = l;
    }
}

// ---------------------------------------------------------------------------
// Transposed split: HT/LT[j*D+i] = split(A[i*D+j]). z-batched over 2 matrices.
__global__ __launch_bounds__(256) void split_t_k(const float* __restrict__ A0,
                                                 unsigned short* __restrict__ H0,
                                                 unsigned short* __restrict__ L0,
                                                 const float* __restrict__ A1,
                                                 unsigned short* __restrict__ H1,
                                                 unsigned short* __restrict__ L1, int D) {
    const float* A = blockIdx.z ? A1 : A0;
    unsigned short* HT = blockIdx.z ? H1 : H0;
    unsigned short* LT = blockIdx.z ? L1 : L0;
    __shared__ float t[32][33];
    const int bx = blockIdx.x * 32, by = blockIdx.y * 32;
    const int x = threadIdx.x, y = threadIdx.y;  // block (32,8)
#pragma unroll
    for (int dy = 0; dy < 32; dy += 8)
        t[y + dy][x] = A[(size_t)(by + y + dy) * D + bx + x];
    __syncthreads();
#pragma unroll
    for (int dy = 0; dy < 32; dy += 8) {
        float v = t[x][y + dy];
        unsigned short h = f2bf(v);
        size_t o = (size_t)(bx + y + dy) * D + by + x;
        HT[o] = h;
        LT[o] = f2bf(v - bf2f(h));
    }
}

// ---------------------------------------------------------------------------
// S = I + h*A + c2*M2 + c3*M3 + c4*M4 ; emit split row-major AND transposed split.
__global__ __launch_bounds__(256) void taylor_t_k(const float* __restrict__ Am,
                                                  const float* __restrict__ M2f,
                                                  const float* __restrict__ M3f,
                                                  const float* __restrict__ M4f,
                                                  unsigned short* __restrict__ Sh,
                                                  unsigned short* __restrict__ Sl,
                                                  unsigned short* __restrict__ STh,
                                                  unsigned short* __restrict__ STl,
                                                  int D, float h) {
    __shared__ float t[32][33];
    const float c2 = 0.5f * h * h;
    const float c3 = h * h * h * (1.0f / 6.0f);
    const float c4 = h * h * h * h * (1.0f / 24.0f);
    const int bx = blockIdx.x * 32, by = blockIdx.y * 32;
    const int x = threadIdx.x, y = threadIdx.y;  // block (32,8)
#pragma unroll
    for (int dy = 0; dy < 32; dy += 8) {
        const int row = by + y + dy, col = bx + x;
        const size_t idx = (size_t)row * D + col;
        float s = h * Am[idx] + c2 * M2f[idx] + c3 * M3f[idx] + c4 * M4f[idx];
        if (row == col) s += 1.0f;
        t[y + dy][x] = s;
        unsigned short hi = f2bf(s);
        Sh[idx] = hi;
        Sl[idx] = f2bf(s - bf2f(hi));
    }
    __syncthreads();
#pragma unroll
    for (int dy = 0; dy < 32; dy += 8) {
        float s = t[x][y + dy];
        size_t o = (size_t)(bx + y + dy) * D + by + x;
        unsigned short hi = f2bf(s);
        STh[o] = hi;
        STl[o] = f2bf(s - bf2f(hi));
    }
}

// ---------------------------------------------------------------------------
// Fast 64x64 NT split GEMM core. C[M,N] = A[M,K] @ B[N,K]^T, inputs hi/lo
// split bf16 (3 MFMAs/position = fp32-class). BK=64, register prefetch,
// padded LDS (LDT=72). Outputs by nullness: Cf32/Chi/Clo row-major [M,N],
// CThi/CTlo transposed [N,M]. M,N %64==0, K %64==0.
struct G64In { const unsigned short *Ahi, *Alo, *Bhi, *Blo; };
struct G64Out { float* Cf32; unsigned short *Chi, *Clo, *CThi, *CTlo; };

__device__ __forceinline__ void g64_core(int bx, int by, int M, int N, int K,
                                         G64In in, G64Out o,
                                         unsigned short* Ash, unsigned short* Asl,
                                         unsigned short* Bsh, unsigned short* Bsl) {
    const int tid = threadIdx.x;
    const int lane = tid & 63;
    const int wave = tid >> 6;
    const int wr = wave >> 1, wc = wave & 1;
    const int row0 = by * 64, col0 = bx * 64;
    const int sr = tid >> 2;          // 0..63 stage row
    const int sk = (tid & 3) * 16;    // 0,16,32,48 (short offset in 64-short chunk)

    const int niter = K >> 6;  // BK=64
    bf16x8 pa0, pa1, pl0, pl1, pb0, pb1, pq0, pq1;
    {
        const unsigned short* ar = in.Ahi + (size_t)(row0 + sr) * K + sk;
        const unsigned short* al = in.Alo + (size_t)(row0 + sr) * K + sk;
        const unsigned short* br = in.Bhi + (size_t)(col0 + sr) * K + sk;
        const unsigned short* bl = in.Blo + (size_t)(col0 + sr) * K + sk;
        pa0 = *(const bf16x8*)ar; pa1 = *(const bf16x8*)(ar + 8);
        pl0 = *(const bf16x8*)al; pl1 = *(const bf16x8*)(al + 8);
        pb0 = *(const bf16x8*)br; pb1 = *(const bf16x8*)(br + 8);
        pq0 = *(const bf16x8*)bl; pq1 = *(const bf16x8*)(bl + 8);
    }

    f32x4 acc[4] = {};  // [mt*2+nt]
    const int mb = wr * 32 + (lane & 15);
    const int nb = wc * 32 + (lane & 15);

    for (int it = 0; it < niter; ++it) {
        __syncthreads();  // prior iteration's LDS consumers done
        *(bf16x8*)&Ash[sr * LDT + sk] = pa0; *(bf16x8*)&Ash[sr * LDT + sk + 8] = pa1;
        *(bf16x8*)&Asl[sr * LDT + sk] = pl0; *(bf16x8*)&Asl[sr * LDT + sk + 8] = pl1;
        *(bf16x8*)&Bsh[sr * LDT + sk] = pb0; *(bf16x8*)&Bsh[sr * LDT + sk + 8] = pb1;
        *(bf16x8*)&Bsl[sr * LDT + sk] = pq0; *(bf16x8*)&Bsl[sr * LDT + sk + 8] = pq1;
        __syncthreads();  // publish

        // issue next-iteration prefetch (latency overlaps MFMA below)
        {
            const int kn = (it + 1 < niter) ? ((it + 1) << 6) : 0;
            const unsigned short* ar = in.Ahi + (size_t)(row0 + sr) * K + kn + sk;
            const unsigned short* al = in.Alo + (size_t)(row0 + sr) * K + kn + sk;
            const unsigned short* br = in.Bhi + (size_t)(col0 + sr) * K + kn + sk;
            const unsigned short* bl = in.Blo + (size_t)(col0 + sr) * K + kn + sk;
            pa0 = *(const bf16x8*)ar; pa1 = *(const bf16x8*)(ar + 8);
            pl0 = *(const bf16x8*)al; pl1 = *(const bf16x8*)(al + 8);
            pb0 = *(const bf16x8*)br; pb1 = *(const bf16x8*)(br + 8);
            pq0 = *(const bf16x8*)bl; pq1 = *(const bf16x8*)(bl + 8);
        }

#pragma unroll
        for (int kh = 0; kh < 2; ++kh) {
            const int kk = kh * 32 + (lane >> 4) * 8;
            bf16x8 ah[2], alx[2], bh[2], blx[2];
#pragma unroll
            for (int t = 0; t < 2; ++t) {
                ah[t]  = *(const bf16x8*)&Ash[(mb + t * 16) * LDT + kk];
                alx[t] = *(const bf16x8*)&Asl[(mb + t * 16) * LDT + kk];
                bh[t]  = *(const bf16x8*)&Bsh[(nb + t * 16) * LDT + kk];
                blx[t] = *(const bf16x8*)&Bsl[(nb + t * 16) * LDT + kk];
            }
#pragma unroll
            for (int mt = 0; mt < 2; ++mt)
#pragma unroll
                for (int nt = 0; nt < 2; ++nt) {
                    acc[mt * 2 + nt] = __builtin_amdgcn_mfma_f32_16x16x32_bf16(
                        ah[mt], bh[nt], acc[mt * 2 + nt], 0, 0, 0);
                    acc[mt * 2 + nt] = __builtin_amdgcn_mfma_f32_16x16x32_bf16(
                        ah[mt], blx[nt], acc[mt * 2 + nt], 0, 0, 0);
                    acc[mt * 2 + nt] = __builtin_amdgcn_mfma_f32_16x16x32_bf16(
                        alx[mt], bh[nt], acc[mt * 2 + nt], 0, 0, 0);
                }
        }
    }

    // epilogue — C/D layout: col=lane&15, row=(lane>>4)*4+reg
#pragma unroll
    for (int mt = 0; mt < 2; ++mt) {
        const int grow = row0 + wr * 32 + mt * 16 + (lane >> 4) * 4;
#pragma unroll
        for (int nt = 0; nt < 2; ++nt) {
            const int gcol = col0 + wc * 32 + nt * 16 + (lane & 15);
            f32x4 a = acc[mt * 2 + nt];
            unsigned short h4[4], l4[4];
#pragma unroll
            for (int i = 0; i < 4; ++i) {
                h4[i] = f2bf(a[i]);
                l4[i] = f2bf(a[i] - bf2f(h4[i]));
            }
            if (o.Cf32) {
#pragma unroll
                for (int i = 0; i < 4; ++i) o.Cf32[(size_t)(grow + i) * N + gcol] = a[i];
            }
            if (o.Chi) {
#pragma unroll
                for (int i = 0; i < 4; ++i) o.Chi[(size_t)(grow + i) * N + gcol] = h4[i];
            }
            if (o.Clo) {
#pragma unroll
                for (int i = 0; i < 4; ++i) o.Clo[(size_t)(grow + i) * N + gcol] = l4[i];
            }
            if (o.CThi) {
                ushort4 u = {h4[0], h4[1], h4[2], h4[3]};
                *(ushort4*)&o.CThi[(size_t)gcol * M + grow] = u;
            }
            if (o.CTlo) {
                ushort4 u = {l4[0], l4[1], l4[2], l4[3]};
                *(ushort4*)&o.CTlo[(size_t)gcol * M + grow] = u;
            }
        }
    }
}

__global__ __launch_bounds__(256) void g64_one(G64In in, G64Out o, int M, int N, int K) {
    __shared__ unsigned short Ash[64 * LDT], Asl[64 * LDT], Bsh[64 * LDT], Bsl[64 * LDT];
    g64_core(blockIdx.x, blockIdx.y, M, N, K, in, o, Ash, Asl, Bsh, Bsl);
}

__global__ __launch_bounds__(256) void g64_dual(G64In i0, G64Out o0, G64In i1, G64Out o1,
                                                int M, int N, int K) {
    __shared__ unsigned short Ash[64 * LDT], Asl[64 * LDT], Bsh[64 * LDT], Bsl[64 * LDT];
    g64_core(blockIdx.x, blockIdx.y, M, N, K, blockIdx.z ? i1 : i0, blockIdx.z ? o1 : o0,
             Ash, Asl, Bsh, Bsl);
}

// ---------------------------------------------------------------------------
// Big bf16 MFMA GEMM (proven): C[M,N] = A[M,K] @ B[N,K]^T (+bias)(relu)
// 128x128 tile, BK=32, 4 waves 2x2 (each 64x64).
template <int RELU, int BIAS, int OUT_BF16>
__global__ __launch_bounds__(256) void gemm_bf16(int M, int N, int K,
                                                 const unsigned short* __restrict__ A,
                                                 const unsigned short* __restrict__ B,
                                                 void* __restrict__ C,
                                                 const float* __restrict__ bias) {
    __shared__ unsigned short As[128 * 32];
    __shared__ unsigned short Bs[128 * 32];

    const int tid = threadIdx.x;
    const int lane = tid & 63;
    const int wave = tid >> 6;
    const int wr = wave >> 1, wc = wave & 1;
    const int row0 = blockIdx.y * 128;
    const int col0 = blockIdx.x * 128;

    const int srow = lane >> 2;
    const int schunk = (lane & 3) * 8;

    f32x4 acc[4][4] = {};

    for (int k0 = 0; k0 < K; k0 += 32) {
        const int r0 = wave * 32;
        GLDS16(A + (size_t)(row0 + r0 + srow) * K + k0 + schunk, &As[r0 * 32]);
        GLDS16(A + (size_t)(row0 + r0 + 16 + srow) * K + k0 + schunk, &As[(r0 + 16) * 32]);
        GLDS16(B + (size_t)(col0 + r0 + srow) * K + k0 + schunk, &Bs[r0 * 32]);
        GLDS16(B + (size_t)(col0 + r0 + 16 + srow) * K + k0 + schunk, &Bs[(r0 + 16) * 32]);
        __syncthreads();

        const int kk = (lane >> 4) * 8;
        const int mbase = wr * 64 + (lane & 15);
        const int nbase = wc * 64 + (lane & 15);
        bf16x8 af[4], bf[4];
#pragma unroll
        for (int t = 0; t < 4; ++t) {
            af[t] = *(const bf16x8*)&As[(mbase + t * 16) * 32 + kk];
            bf[t] = *(const bf16x8*)&Bs[(nbase + t * 16) * 32 + kk];
        }
#pragma unroll
        for (int mt = 0; mt < 4; ++mt)
#pragma unroll
            for (int nt = 0; nt < 4; ++nt)
                acc[mt][nt] = __builtin_amdgcn_mfma_f32_16x16x32_bf16(af[mt], bf[nt],
                                                                      acc[mt][nt], 0, 0, 0);
        __syncthreads();
    }

#pragma unroll
    for (int mt = 0; mt < 4; ++mt) {
        const int grow = row0 + wr * 64 + mt * 16 + (lane >> 4) * 4;
#pragma unroll
        for (int nt = 0; nt < 4; ++nt) {
            const int gcol = col0 + wc * 64 + nt * 16 + (lane & 15);
            const float bv = BIAS ? bias[gcol] : 0.0f;
#pragma unroll
            for (int i = 0; i < 4; ++i) {
                float v = acc[mt][nt][i] + bv;
                if (RELU) v = fmaxf(v, 0.0f);
                const size_t off = (size_t)(grow + i) * N + gcol;
                if (OUT_BF16)
                    ((unsigned short*)C)[off] = f2bf(v);
                else
                    ((float*)C)[off] = v;
            }
        }
    }
}

// ---------------------------------------------------------------------------
// 64x64 NT bf16 GEMM, fp32 out + bias (for y: N=256 -> 256 blocks). Proven.
__global__ __launch_bounds__(256) void gemm64nt_f32(int M, int N, int K,
                                                    const unsigned short* __restrict__ A,
                                                    const unsigned short* __restrict__ B,
                                                    float* __restrict__ C,
                                                    const float* __restrict__ bias) {
    __shared__ unsigned short As[64 * 32];
    __shared__ unsigned short Bs[64 * 32];
    const int tid = threadIdx.x;
    const int lane = tid & 63;
    const int wave = tid >> 6;
    const int wr = wave >> 1, wc = wave & 1;
    const int row0 = blockIdx.y * 64;
    const int col0 = blockIdx.x * 64;
    const int r = tid >> 2, kq = (tid & 3) * 8;

    f32x4 acc[4] = {};

    for (int k0 = 0; k0 < K; k0 += 32) {
        bf16x8 av = *(const bf16x8*)(A + (size_t)(row0 + r) * K + k0 + kq);
        bf16x8 bv = *(const bf16x8*)(B + (size_t)(col0 + r) * K + k0 + kq);
        __syncthreads();
        *(bf16x8*)&As[r * 32 + kq] = av;
        *(bf16x8*)&Bs[r * 32 + kq] = bv;
        __syncthreads();

        const int kk = (lane >> 4) * 8;
        const int mb = wr * 32 + (lane & 15);
        const int nb = wc * 32 + (lane & 15);
        bf16x8 af[2], bf[2];
#pragma unroll
        for (int t = 0; t < 2; ++t) {
            af[t] = *(const bf16x8*)&As[(mb + t * 16) * 32 + kk];
            bf[t] = *(const bf16x8*)&Bs[(nb + t * 16) * 32 + kk];
        }
#pragma unroll
        for (int mt = 0; mt < 2; ++mt)
#pragma unroll
            for (int nt = 0; nt < 2; ++nt)
                acc[mt * 2 + nt] = __builtin_amdgcn_mfma_f32_16x16x32_bf16(
                    af[mt], bf[nt], acc[mt * 2 + nt], 0, 0, 0);
    }

#pragma unroll
    for (int mt = 0; mt < 2; ++mt) {
        const int grow = row0 + wr * 32 + mt * 16 + (lane >> 4) * 4;
#pragma unroll
        for (int nt = 0; nt < 2; ++nt) {
            const int gcol = col0 + wc * 32 + nt * 16 + (lane & 15);
            const float bv = bias ? bias[gcol] : 0.0f;
#pragma unroll
            for (int i = 0; i < 4; ++i)
                C[(size_t)(grow + i) * N + gcol] = acc[mt * 2 + nt][i] + bv;
        }
    }
}

// ---------------------------------------------------------------------------
extern "C" void kernel_launch(void* const* d_in, const int* in_sizes, int n_in,
                              void* d_out, int out_size, void* d_ws, size_t ws_size,
                              hipStream_t stream) {
    const float* X  = (const float*)d_in[0];  // [B, Dx]
    const float* P  = (const float*)d_in[1];  // [Dz, Dx]
    const float* Am = (const float*)d_in[2];  // [Dz, Dz]
    const float* W1 = (const float*)d_in[3];  // [H, Dz]
    const float* b1 = (const float*)d_in[4];
    const float* W2 = (const float*)d_in[5];  // [H, H]
    const float* b2 = (const float*)d_in[6];
    const float* W3 = (const float*)d_in[7];  // [Dy, H]
    const float* b3 = (const float*)d_in[8];
    float* out = (float*)d_out;               // [B, Dy] fp32

    const float h = 1.0f / (float)NSTEPS;
    const size_t S = (size_t)DZ * DZ;  // 262144

    // ---- workspace carve-up (~64 MB) ----
    char* p = (char*)d_ws;
    auto alloc_f = [&](size_t n) { float* r = (float*)p; p += n * 4; return r; };
    auto alloc_h = [&](size_t n) { unsigned short* r = (unsigned short*)p; p += ((n * 2 + 15) & ~15ull); return r; };
    unsigned short* Xb   = alloc_h((size_t)BDIM * DX);
    unsigned short* W2b  = alloc_h((size_t)HD * HD);
    unsigned short* W3b  = alloc_h((size_t)DY * HD);
    unsigned short* W1h  = alloc_h((size_t)HD * DZ);
    unsigned short* W1l  = alloc_h((size_t)HD * DZ);
    unsigned short* Ah   = alloc_h(S);
    unsigned short* Al   = alloc_h(S);
    unsigned short* ATh  = alloc_h(S);
    unsigned short* ATl  = alloc_h(S);
    unsigned short* PTh  = alloc_h(S);
    unsigned short* PTl  = alloc_h(S);
    float* M2f = alloc_f(S);
    float* M3f = alloc_f(S);
    float* M4f = alloc_f(S);
    unsigned short* M2h  = alloc_h(S);
    unsigned short* M2l  = alloc_h(S);
    unsigned short* M2Th = alloc_h(S);
    unsigned short* M2Tl = alloc_h(S);
    unsigned short* Shb[2]  = {alloc_h(S), alloc_h(S)};
    unsigned short* Slb[2]  = {alloc_h(S), alloc_h(S)};
    unsigned short* SThb[2] = {alloc_h(S), alloc_h(S)};
    unsigned short* STlb[2] = {alloc_h(S), alloc_h(S)};
    unsigned short* RTh  = alloc_h(S);
    unsigned short* RTl  = alloc_h(S);
    unsigned short* C1b  = alloc_h((size_t)HD * DZ);
    unsigned short* h1b  = alloc_h((size_t)BDIM * HD);
    unsigned short* h2b  = alloc_h((size_t)BDIM * HD);

    // ---- 1 launch: input converts/splits (row-major) ----
    CvtJobs J;
    J.src[0] = X;  J.hi[0] = Xb;  J.lo[0] = nullptr; J.n4[0] = BDIM * DX / 4;
    J.src[1] = W2; J.hi[1] = W2b; J.lo[1] = nullptr; J.n4[1] = HD * HD / 4;
    J.src[2] = W3; J.hi[2] = W3b; J.lo[2] = nullptr; J.n4[2] = DY * HD / 4;
    J.src[3] = W1; J.hi[3] = W1h; J.lo[3] = W1l;     J.n4[3] = HD * DZ / 4;
    J.src[4] = Am; J.hi[4] = Ah;  J.lo[4] = Al;      J.n4[4] = (int)(S / 4);
    cvt_multi_k<<<dim3(HD * HD / 4 / 256, 5), 256, 0, stream>>>(J);

    // transposed splits: A^T, P^T
    split_t_k<<<dim3(DZ / 32, DZ / 32, 2), dim3(32, 8), 0, stream>>>(
        Am, ATh, ATl, P, PTh, PTl, DZ);

    dim3 g8(DZ / 64, DZ / 64);  // 8x8 = 64 blocks
    const G64Out ONULL = {nullptr, nullptr, nullptr, nullptr, nullptr};

    // M2 = A@A : NT(A, AT) -> f32 + split + splitT
    {
        G64In i{Ah, Al, ATh, ATl};
        G64Out o{M2f, M2h, M2l, M2Th, M2Tl};
        g64_one<<<g8, 256, 0, stream>>>(i, o, DZ, DZ, DZ);
    }
    // M3 = M2@A : NT(M2, AT) -> f32 ; M4 = M2@M2 : NT(M2, M2T) -> f32  (z-batched)
    {
        G64In i0{M2h, M2l, ATh, ATl};
        G64Out o0 = ONULL; o0.Cf32 = M3f;
        G64In i1{M2h, M2l, M2Th, M2Tl};
        G64Out o1 = ONULL; o1.Cf32 = M4f;
        g64_dual<<<dim3(DZ / 64, DZ / 64, 2), 256, 0, stream>>>(i0, o0, i1, o1, DZ, DZ, DZ);
    }
    // S0 = taylor4 (split + splitT)
    taylor_t_k<<<dim3(DZ / 32, DZ / 32), dim3(32, 8), 0, stream>>>(
        Am, M2f, M3f, M4f, Shb[0], Slb[0], SThb[0], STlb[0], DZ, h);
    // Q = S^64 via 6 squarings: S' = NT(S, ST) -> split + splitT
    int cur = 0;
    for (int s = 0; s < 6; ++s) {
        G64In i{Shb[cur], Slb[cur], SThb[cur], STlb[cur]};
        G64Out o{nullptr, Shb[1 - cur], Slb[1 - cur], SThb[1 - cur], STlb[1 - cur]};
        g64_one<<<g8, 256, 0, stream>>>(i, o, DZ, DZ, DZ);
        cur ^= 1;
    }
    // R = Q@P : NT(Q, PT) -> R^T split only
    {
        G64In i{Shb[cur], Slb[cur], PTh, PTl};
        G64Out o = ONULL; o.CThi = RTh; o.CTlo = RTl;
        g64_one<<<g8, 256, 0, stream>>>(i, o, DZ, DZ, DZ);
    }
    // C1 = W1@R : NT(W1, RT) -> hi row-major [H, Dx] (B-operand for h1)
    {
        G64In i{W1h, W1l, RTh, RTl};
        G64Out o = ONULL; o.Chi = C1b;
        g64_one<<<dim3(DZ / 64, HD / 64), 256, 0, stream>>>(i, o, HD, DZ, DZ);
    }

    // h1 = relu(X @ C1^T + b1)   [B, H], K=Dx
    gemm_bf16<1, 1, 1><<<dim3(HD / 128, BDIM / 128), 256, 0, stream>>>(
        BDIM, HD, DX, Xb, C1b, h1b, b1);
    // h2 = relu(h1 @ W2^T + b2)  [B, H]
    gemm_bf16<1, 1, 1><<<dim3(HD / 128, BDIM / 128), 256, 0, stream>>>(
        BDIM, HD, HD, h1b, W2b, h2b, b2);
    // y = h2 @ W3^T + b3         [B, Dy] fp32 out — 64-tile => 256 blocks
    gemm64nt_f32<<<dim3(DY / 64, BDIM / 64), 256, 0, stream>>>(
        BDIM, DY, HD, h2b, W3b, out, b3);
}